// Round 2
// 95.442 us; speedup vs baseline: 1.0058x; 1.0058x over previous
//
#include <hip/hip_runtime.h>

// MVB (minimum-variance beamformer), fp32. Round 12: resubmit of R11
// (round 1 bench failed with "MI355X container failed twice" — infra flake,
// no kernel verdict). Kernel unchanged; audit notes below.
//
// R11 design: LDS-banked gather with double-buffered global_load_lds DMA.
// R10's global-gather kernel is bounded by L1 divergent-request service:
// 32768 random lane-gathers/CU at ~1 addr/cycle ~= 13.6 us floor (+ VALU)
// => ~24.5 us. LDS serves the same random 8-B gathers at 32-bank parallelism
// (~2x conflict cost => ~2.5 us). R7's LDS attempt was staging-bound (VGPR
// round-trip); this stages via __builtin_amdgcn_global_load_lds (direct DMA,
// 16B/lane), double-buffered 2 x 32KB (8 rf rows per chunk), ONE barrier per
// chunk, so staging latency hides under the previous chunk's gather+FMA burst.
//
// Hazard audit (round 1): every stage into a buffer is issued after the
// barrier ending all reads of that buffer; every gather is after the barrier
// draining its staging vmcnt; LDS = 64 KB exactly; all global accesses
// in-bounds; barriers on uniform control flow.
//
// Chunk = 8 channels; the mod-16 window ring keeps compile-time indices via
// template<Q16 in {0,8}>. Post-state (F/win/head/Sall) identical to R10;
// solve phase unchanged (verified absmax 9.8e-4).

namespace {

constexpr int kB  = 2;
constexpr int kC  = 128;
constexpr int kNS = 1024;
constexpr int kNZ = 256;
constexpr int kNX = 128;
constexpr int kZX = kNZ * kNX;        // 32768
constexpr int kTPB = 256;

// packed upper-triangular index, l <= k, 16x16 -> 136 entries
__device__ __host__ constexpr int tri(int l, int k) {
  return l * 16 - (l * (l - 1)) / 2 + (k - l);
}

// Stage 8 rf rows (32 KB, contiguous in global) into LDS via direct DMA.
// Per sweep: 4 waves x 64 lanes x 16 B = 4 KB; 8 sweeps = 32 KB.
// LDS dest is wave-uniform base; lanes land at base + lane*16 (linear layout).
__device__ __forceinline__ void stage8(const float* __restrict__ src,
                                       float* dst, int w, int lane) {
  const int wbase = w * 1024;          // bytes, per-wave segment within sweep
#pragma unroll
  for (int s = 0; s < 8; ++s) {
    const int sb = wbase + s * 4096;
    __builtin_amdgcn_global_load_lds(
        (const __attribute__((address_space(1))) void*)((const char*)src + sb +
                                                        lane * 16),
        (__attribute__((address_space(3))) void*)((char*)dst + sb), 16, 0, 0);
  }
}

// Gather + window-FMA for 8 channels resident in LDS buffer buf[8][1024].
// Q16 = (chunk*8) & 15 -> ring slot base, compile-time. HEAD for channels<16.
template <int Q16, bool HEAD>
__device__ __forceinline__ void gather8(
    const float* __restrict__ buf, const float (&dr)[8], float kk, float base,
    float (&F)[16], float (&win)[16], float (&head)[16], float& Sall) {
  float fr[8];
  int ix[8];
#pragma unroll
  for (int r = 0; r < 8; ++r) {
    float pos = fmaf(kk, dr[r], base);
    pos = fminf(fmaxf(pos, 0.0f), 1023.0f);
    int i0 = (int)pos;                 // pos >= 0: trunc == floor
    i0 = min(i0, kNS - 2);             // pos==1023 -> frac==1.0
    fr[r] = pos - (float)i0;
    ix[r] = r * 1024 + i0;
  }
  // 8 independent ds_read2_b32 pairs (random banks, ~2x conflict cost)
  float v0[8], v1[8];
#pragma unroll
  for (int r = 0; r < 8; ++r) {
    v0[r] = buf[ix[r]];
    v1[r] = buf[ix[r] + 1];
  }
#pragma unroll
  for (int r = 0; r < 8; ++r) {
    const int c = Q16 + r;             // ring slot == channel & 15
    float v = fmaf(fr[r], v1[r] - v0[r], v0[r]);
    Sall += v;
    F[0] = fmaf(v, v, F[0]);
    if constexpr (HEAD) {
#pragma unroll
      for (int d = 1; d <= c; ++d) F[d] = fmaf(v, win[c - d], F[d]);
      head[c] = v;
    } else {
#pragma unroll
      for (int d = 1; d < 16; ++d) F[d] = fmaf(v, win[(c - d) & 15], F[d]);
    }
    win[c] = v;
  }
}

// ---------------- Fused kernel: DMA-staged LDS gather + solve --------------
__global__ __launch_bounds__(kTPB, 1) void mvb_kernel(
    const float* __restrict__ rf, const float* __restrict__ t0,
    const float* __restrict__ d_tx, const float* __restrict__ d_rx,
    const float* __restrict__ fs_p, const float* __restrict__ c0_p,
    float* __restrict__ out) {
  __shared__ float lds[2][8 * 1024];   // 2 x 32 KB double buffer

  const int tid = threadIdx.x;
  const int w = tid >> 6, lane = tid & 63;
  const int b = blockIdx.x >> 7;       // 256 blocks: b in {0,1}
  const int z = ((blockIdx.x & 127) << 1) + (tid >> 7);
  const int x = tid & 127;
  const int pix = (int)((size_t)b * kZX + z * kNX + x);

  const float fs = fs_p[0];
  const float c0 = c0_p[0];
  const float kk = fs / c0;
  const float base = fs * (d_tx[pix] / c0 + t0[b]);

  const float* rfb = rf + (size_t)b * kC * kNS;
  const float* drxp = d_rx + (size_t)z * kNX + x;   // + c*kZX per channel

  float F[16], win[16], head[16];
  float Sall = 0.0f;
#pragma unroll
  for (int i = 0; i < 16; ++i) F[i] = 0.0f;

  float dr[8], drn[8];

  // ---- prologue: stage chunk 0, load its delays ----
  stage8(rfb, lds[0], w, lane);
#pragma unroll
  for (int r = 0; r < 8; ++r) dr[r] = drxp[(size_t)r * kZX];
  __syncthreads();                     // drains vmcnt -> chunk 0 resident

  // ---- chunk 0 (HEAD, ring base 0) ----
  stage8(rfb + 8 * kNS, lds[1], w, lane);
#pragma unroll
  for (int r = 0; r < 8; ++r) drn[r] = drxp[(size_t)(8 + r) * kZX];
  gather8<0, true>(lds[0], dr, kk, base, F, win, head, Sall);
  __syncthreads();
#pragma unroll
  for (int r = 0; r < 8; ++r) dr[r] = drn[r];

  // ---- chunk 1 (HEAD, ring base 8) ----
  stage8(rfb + 16 * kNS, lds[0], w, lane);
#pragma unroll
  for (int r = 0; r < 8; ++r) drn[r] = drxp[(size_t)(16 + r) * kZX];
  gather8<8, true>(lds[1], dr, kk, base, F, win, head, Sall);
  __syncthreads();
#pragma unroll
  for (int r = 0; r < 8; ++r) dr[r] = drn[r];

  // ---- chunks 2..15, double-buffered, one barrier each ----
#pragma unroll 1
  for (int qp = 1; qp < 8; ++qp) {
    // even chunk q = 2*qp -> lds[0]; prefetch chunk 2*qp+1 -> lds[1]
    stage8(rfb + (size_t)(2 * qp + 1) * 8 * kNS, lds[1], w, lane);
#pragma unroll
    for (int r = 0; r < 8; ++r)
      drn[r] = drxp[(size_t)((2 * qp + 1) * 8 + r) * kZX];
    gather8<0, false>(lds[0], dr, kk, base, F, win, head, Sall);
    __syncthreads();
#pragma unroll
    for (int r = 0; r < 8; ++r) dr[r] = drn[r];

    // odd chunk q = 2*qp+1 -> lds[1]; prefetch chunk 2*qp+2 -> lds[0]
    if (qp < 7) {
      stage8(rfb + (size_t)(2 * qp + 2) * 8 * kNS, lds[0], w, lane);
#pragma unroll
      for (int r = 0; r < 8; ++r)
        drn[r] = drxp[(size_t)((2 * qp + 2) * 8 + r) * kZX];
    }
    gather8<8, false>(lds[1], dr, kk, base, F, win, head, Sall);
    if (qp < 7) {
      __syncthreads();
#pragma unroll
      for (int r = 0; r < 8; ++r) dr[r] = drn[r];
    }
  }
  // now: head[i] = xf[i], win[i] = xf[112+i], F[d] = sum_j xf[j]*xf[j-d]

  // ---- assemble R (unscaled; packed upper triangle) ----
  float Ru[136];
#pragma unroll
  for (int d = 0; d < 16; ++d) {
    float t0s = 0.0f;                  // tail beyond window of l=0
#pragma unroll
    for (int i = d + 1; i < 16; ++i) t0s = fmaf(win[i - d], win[i], t0s);
    Ru[tri(0, d)] = F[d] - t0s;
#pragma unroll
    for (int l = 1; l < 16 - d; ++l)
      Ru[tri(l, l + d)] = Ru[tri(l - 1, l - 1 + d)] -
                          head[l - 1] * head[l - 1 + d] +
                          win[l] * win[l + d];
  }

  // diagonal loading: += DL * trace/16
  float tr = 0.0f;
#pragma unroll
  for (int l = 0; l < 16; ++l) tr += Ru[tri(l, l)];
  const float dl = tr * (0.05f / 16.0f);
#pragma unroll
  for (int l = 0; l < 16; ++l) Ru[tri(l, l)] += dl;

  // x (unscaled window sums): X[l] = sum_{j=l}^{l+112} xf[j]
  float X[16];
  {
    float s = Sall;
#pragma unroll
    for (int i = 1; i < 16; ++i) s -= win[i];
    X[0] = s;
#pragma unroll
    for (int l = 1; l < 16; ++l) X[l] = X[l - 1] - head[l - 1] + win[l];
  }

  // ---- Cholesky R = L L^T (rsqrt form), L[i][j] at Ru[tri(j,i)] ----
  float inv[16];
#pragma unroll
  for (int j = 0; j < 16; ++j) {
    float d = Ru[tri(j, j)];
#pragma unroll
    for (int p = 0; p < j; ++p) d = fmaf(-Ru[tri(p, j)], Ru[tri(p, j)], d);
    inv[j] = rsqrtf(d);
#pragma unroll
    for (int i = j + 1; i < 16; ++i) {
      float s = Ru[tri(j, i)];
#pragma unroll
      for (int p = 0; p < j; ++p) s = fmaf(-Ru[tri(p, i)], Ru[tri(p, j)], s);
      Ru[tri(j, i)] = s * inv[j];
    }
  }

  // forward solve L y = 1
  float yv[16];
#pragma unroll
  for (int i = 0; i < 16; ++i) {
    float s = 1.0f;
#pragma unroll
    for (int j = 0; j < i; ++j) s = fmaf(-Ru[tri(j, i)], yv[j], s);
    yv[i] = s * inv[i];
  }
  // back solve L^T u = y
  float u[16];
#pragma unroll
  for (int i = 15; i >= 0; --i) {
    float s = yv[i];
#pragma unroll
    for (int j = i + 1; j < 16; ++j) s = fmaf(-Ru[tri(i, j)], u[j], s);
    u[i] = s * inv[i];
  }

  float su = 0.0f, dot = 0.0f;
#pragma unroll
  for (int i = 0; i < 16; ++i) {
    su += u[i];
    dot = fmaf(u[i], X[i], dot);
  }
  // y = dot/(M*su + 1e-10)  (matches reference up to scale algebra)
  out[pix] = dot / (113.0f * su + 1e-10f);
}

}  // namespace

extern "C" void kernel_launch(void* const* d_in, const int* in_sizes, int n_in,
                              void* d_out, int out_size, void* d_ws,
                              size_t ws_size, hipStream_t stream) {
  const float* rf   = (const float*)d_in[0];
  const float* t0   = (const float*)d_in[1];
  const float* d_tx = (const float*)d_in[2];
  const float* d_rx = (const float*)d_in[3];
  const float* fs   = (const float*)d_in[4];
  // d_in[5] = f0 (unused), d_in[7] = apod (unused by reference)
  const float* c0   = (const float*)d_in[6];
  float* out = (float*)d_out;

  hipLaunchKernelGGL(mvb_kernel, dim3(kB * kNZ / 2), dim3(kTPB), 0, stream,
                     rf, t0, d_tx, d_rx, fs, c0, out);
}